// Round 16
// baseline (86.867 us; speedup 1.0000x reference)
//
#include <hip/hip_runtime.h>
#include <hip/hip_bf16.h>

// LiftedStructureLoss on MI355X (gfx950)
// N=8192, D=128 fp32 embeddings; int labels (0..99); scalar fp32 out.
//
// 3 launches:
//   setup:  prep (sq, bf16, log2e-prescaled; zero sum_exp) + bucket block
//           (hist/scan/scatter + PAIR-SLOT scan: offsPairs[L], pairsTotal)
//   pass1:  grid nT+NL. Blocks <nT: upper-triangle 128x128 tiles (unmodified
//           hot path) -> atomic sum_exp of exp(-d) over negatives.
//           Blocks >=nT: within-label Gram; every pair (a<b) writes its
//           (d, i,j) record to a DETERMINISTIC slot -> no atomics.
//   pass2:  grid-stride over pair records: relu(1+log(se_i+se_j)+d)^2;
//           ticket: last block -> out = sum / npairs / 2.
//
// Scaling: ebf/sq carry log2e so exp2(-sqrt(d2s)) = exp(-d); true d =
// sqrt(d2s)*ln2. MARGIN's e^1 folds into the +1 inside pass2's log term.

typedef __attribute__((ext_vector_type(8))) short bf16x8;
typedef __attribute__((ext_vector_type(4))) float f32x4;

#if __has_builtin(__builtin_amdgcn_exp2f)
#define EXP2F __builtin_amdgcn_exp2f
#else
#define EXP2F exp2f
#endif

#define PAIR_CAP (1u << 20)   // 1M records (8MB); actual ~332K

__device__ __forceinline__ unsigned short f2bf(float f) {
    unsigned u = __float_as_uint(f);
    u += 0x7fffu + ((u >> 16) & 1u);   // round-to-nearest-even
    return (unsigned short)(u >> 16);
}

// Blocks 0..nPrep-1: prep 32 rows + zero sum_exp slice (block 0: ticket).
// Block nPrep: bucket (256 thr): hist, idx scan, PAIR scan, scatter.
__global__ __launch_bounds__(256) void setup_kernel(
    const float* __restrict__ e, const int* __restrict__ labels,
    float* __restrict__ sq, unsigned* __restrict__ ebf,
    float* __restrict__ sum_exp,
    int* __restrict__ counts_out, int* __restrict__ offsets_out,
    int* __restrict__ offsPairs_out, unsigned* __restrict__ pairsTotal,
    int* __restrict__ idxbuf, unsigned* __restrict__ ticket, int N)
{
    const int tid = threadIdx.x;
    const float LOG2E = 1.44269504088896341f;
    if ((int)blockIdx.x < (int)gridDim.x - 1) {
        const int lane = tid & 63, wid = tid >> 6;
        if (blockIdx.x == 0 && tid == 0) *ticket = 0u;
        if (tid < 32) sum_exp[blockIdx.x * 32 + tid] = 0.f;
        const int rowbase = (blockIdx.x * 4 + wid) * 8;
        #pragma unroll
        for (int it = 0; it < 8; ++it) {
            int row = rowbase + it;
            if (row >= N) break;
            float2 v = ((const float2*)(e + (size_t)row * 128))[lane];
            v.x *= LOG2E; v.y *= LOG2E;
            float s = v.x * v.x + v.y * v.y;
            #pragma unroll
            for (int off = 1; off < 64; off <<= 1) s += __shfl_xor(s, off, 64);
            if (lane == 0) sq[row] = s;
            unsigned bits = (unsigned)f2bf(v.x) | ((unsigned)f2bf(v.y) << 16);
            ebf[(size_t)row * 64 + lane] = bits;
        }
    } else {
        __shared__ int cnt[256];
        __shared__ int off[256];
        __shared__ int po[256];
        cnt[tid] = 0;
        __syncthreads();
        for (int i = tid; i < N; i += 256)
            atomicAdd(&cnt[(unsigned)labels[i] & 255u], 1);
        __syncthreads();
        if (tid < 64) {
            int base = tid * 4;
            int c0 = cnt[base], c1 = cnt[base+1], c2 = cnt[base+2], c3 = cnt[base+3];
            // index-offset scan
            int s = c0 + c1 + c2 + c3;
            int v = s;
            #pragma unroll
            for (int d = 1; d < 64; d <<= 1) {
                int u = __shfl_up(v, d, 64);
                if (tid >= d) v += u;
            }
            int excl = v - s;
            off[base]     = excl;
            off[base + 1] = excl + c0;
            off[base + 2] = excl + c0 + c1;
            off[base + 3] = excl + c0 + c1 + c2;
            // pair-slot scan: c*(c-1)/2 per label
            int p0 = c0 * (c0 - 1) / 2, p1 = c1 * (c1 - 1) / 2;
            int p2 = c2 * (c2 - 1) / 2, p3 = c3 * (c3 - 1) / 2;
            int ps = p0 + p1 + p2 + p3;
            int pv = ps;
            #pragma unroll
            for (int d = 1; d < 64; d <<= 1) {
                int u = __shfl_up(pv, d, 64);
                if (tid >= d) pv += u;
            }
            int pexcl = pv - ps;
            po[base]     = pexcl;
            po[base + 1] = pexcl + p0;
            po[base + 2] = pexcl + p0 + p1;
            po[base + 3] = pexcl + p0 + p1 + p2;
            if (tid == 63) *pairsTotal = (unsigned)pv;   // grand total
        }
        __syncthreads();
        counts_out[tid]    = cnt[tid];
        offsets_out[tid]   = off[tid];
        offsPairs_out[tid] = po[tid];
        cnt[tid] = off[tid];               // reuse as cursor
        __syncthreads();
        for (int i = tid; i < N; i += 256) {
            int l = (unsigned)labels[i] & 255u;
            int p = atomicAdd(&cnt[l], 1);
            idxbuf[p] = i;
        }
    }
}

// Mega PASS 1: blocks [0,nT) = tile path (untouched hot loop);
// blocks [nT, nT+NL) = within-label pair-distance blocks (deterministic slots).
__global__ __launch_bounds__(512) void pass1_kernel(
    const unsigned short* __restrict__ ebf,
    const float* __restrict__ sq,
    const int* __restrict__ labels,
    float* __restrict__ sum_exp,
    const int* __restrict__ idxbuf,
    const int* __restrict__ offsets,
    const int* __restrict__ counts,
    const int* __restrict__ offsPairs,
    uint2* __restrict__ pairs,
    int N, int nCb, int nT)
{
    __shared__ __align__(16) char a_tile[128 * 128];
    __shared__ __align__(16) char b_tile[128 * 128];
    __shared__ float rowsum[128];
    __shared__ float colsum[128];

    const int tid = threadIdx.x;
    const int lane = tid & 63, wid = tid >> 6;
    const float LN2 = 0.69314718055994531f;
    const int wm = (wid >> 2) * 64, wn = (wid & 3) * 32;
    const int lhi = lane >> 4, llo = lane & 15;
    const char* ebfB = (const char*)ebf;

    if ((int)blockIdx.x < nT) {
        // ================= tile path (R13, unmodified) =================
        const int t = blockIdx.x;
        int bi = (int)((2.f * nCb + 1.f - __builtin_amdgcn_sqrtf(
                       (2.f * nCb + 1.f) * (2.f * nCb + 1.f) - 8.f * t)) * 0.5f);
        if (bi < 0) bi = 0;
        if (bi > nCb - 1) bi = nCb - 1;
        while (bi + 1 <= nCb - 1 && (bi + 1) * (2 * nCb - bi) / 2 <= t) ++bi;
        while (bi > 0 && bi * (2 * nCb - bi + 1) / 2 > t) --bi;
        const int bj = bi + (t - bi * (2 * nCb - bi + 1) / 2);
        const bool diag = (bi == bj);
        const int brow = bi * 128, bcol = bj * 128;

        if (tid < 128) { rowsum[tid] = 0.f; colsum[tid] = 0.f; }

        f32x4 acc[4][2];
        #pragma unroll
        for (int m = 0; m < 4; ++m)
            #pragma unroll
            for (int n = 0; n < 2; ++n)
                acc[m][n] = (f32x4){0.f, 0.f, 0.f, 0.f};

        #pragma unroll
        for (int c = 0; c < 2; ++c) {
            #pragma unroll
            for (int k = 0; k < 4; ++k) {
                int s = wid * 256 + k * 64;
                int tsel = s >> 10;
                int ls = s & 1023;
                int sl = ls + lane;
                int r = sl >> 3, j = sl & 7;
                int grow = (tsel ? bcol : brow) + r;
                const void* g = ebfB + ((size_t)grow << 8) + c * 128 + ((j ^ (r & 7)) << 4);
                char* l = (tsel ? b_tile : a_tile) + ls * 16;
                __builtin_amdgcn_global_load_lds(
                    (const __attribute__((address_space(1))) unsigned*)g,
                    (__attribute__((address_space(3))) unsigned*)l, 16, 0, 0);
            }
            __syncthreads();

            #pragma unroll
            for (int h = 0; h < 2; ++h) {
                const int cb = h * 64 + lhi * 16;
                bf16x8 af[4], bfr[2];
                #pragma unroll
                for (int m = 0; m < 4; ++m) {
                    int r = wm + m * 16 + llo;
                    af[m] = *(const bf16x8*)(a_tile + r * 128 + (cb ^ ((r & 7) << 4)));
                }
                #pragma unroll
                for (int n = 0; n < 2; ++n) {
                    int r = wn + n * 16 + llo;
                    bfr[n] = *(const bf16x8*)(b_tile + r * 128 + (cb ^ ((r & 7) << 4)));
                }
                #pragma unroll
                for (int m = 0; m < 4; ++m)
                    #pragma unroll
                    for (int n = 0; n < 2; ++n)
                        acc[m][n] = __builtin_amdgcn_mfma_f32_16x16x32_bf16(af[m], bfr[n], acc[m][n], 0, 0, 0);
            }
            __syncthreads();
        }

        const int rowbase = brow + wm;
        float sqr[4][4]; int labr[4][4];
        #pragma unroll
        for (int m = 0; m < 4; ++m)
            #pragma unroll
            for (int r = 0; r < 4; ++r) {
                int row = rowbase + m * 16 + lhi * 4 + r;
                sqr[m][r] = sq[row];
                labr[m][r] = labels[row];
            }
        float sqc[2]; int labc[2];
        #pragma unroll
        for (int n = 0; n < 2; ++n) {
            int col = bcol + wn + n * 16 + llo;
            sqc[n] = sq[col];
            labc[n] = labels[col];
        }

        float wsum[4][4] = {};
        float csum[2] = {};
        #pragma unroll
        for (int m = 0; m < 4; ++m)
            #pragma unroll
            for (int n = 0; n < 2; ++n)
                #pragma unroll
                for (int r = 0; r < 4; ++r) {
                    float g = acc[m][n][r];
                    float d2 = fmaxf(fmaf(-2.f, g, sqr[m][r] + sqc[n]), 0.f);
                    float dist = __builtin_amdgcn_sqrtf(d2);   // log2e * d
                    float w = (labr[m][r] != labc[n]) ? EXP2F(0.f - dist) : 0.f;
                    wsum[m][r] += w;
                    csum[n] += w;
                }
        #pragma unroll
        for (int m = 0; m < 4; ++m)
            #pragma unroll
            for (int r = 0; r < 4; ++r) {
                float s = wsum[m][r];
                #pragma unroll
                for (int off = 1; off < 16; off <<= 1) s += __shfl_xor(s, off, 64);
                if (llo == 0)
                    atomicAdd(&rowsum[wm + m * 16 + lhi * 4 + r], s);
            }
        if (!diag) {
            #pragma unroll
            for (int n = 0; n < 2; ++n) {
                float s = csum[n];
                s += __shfl_xor(s, 16, 64);
                s += __shfl_xor(s, 32, 64);
                if (lhi == 0)
                    atomicAdd(&colsum[wn + n * 16 + llo], s);
            }
        }
        __syncthreads();
        if (tid < 128) {
            unsafeAtomicAdd(&sum_exp[brow + tid], rowsum[tid]);
            if (!diag)
                unsafeAtomicAdd(&sum_exp[bcol + tid], colsum[tid]);
        }
    } else {
        // ============ within-label pair-distance path ============
        const int L = blockIdx.x - nT;
        const int cnt = counts[L], offs = offsets[L];
        const int pOffs = offsPairs[L];
        if (cnt < 2) return;
        const int nSub = (cnt + 127) >> 7;

        for (int si = 0; si < nSub; ++si)
        for (int sj = si; sj < nSub; ++sj) {
            const int baseA = offs + si * 128, baseB = offs + sj * 128;
            const int cntA = min(128, cnt - si * 128);
            const int cntB = min(128, cnt - sj * 128);

            f32x4 acc[4][2];
            #pragma unroll
            for (int m = 0; m < 4; ++m)
                #pragma unroll
                for (int n = 0; n < 2; ++n)
                    acc[m][n] = (f32x4){0.f, 0.f, 0.f, 0.f};

            for (int c = 0; c < 2; ++c) {
                // reg-staged gather: 2048 slots over 512 thr
                #pragma unroll
                for (int i2 = 0; i2 < 4; ++i2) {
                    int sl = tid + i2 * 512;
                    int tsel = sl >> 10;
                    int s = sl & 1023;
                    int r = s >> 3, j = s & 7;
                    int base = tsel ? baseB : baseA;
                    int cc = tsel ? cntB : cntA;
                    int gr = idxbuf[base + min(r, cc - 1)];
                    uint4 v = *(const uint4*)(ebfB + ((size_t)gr << 8) + c * 128 + (j << 4));
                    char* tp = tsel ? b_tile : a_tile;
                    *(uint4*)(tp + r * 128 + ((j << 4) ^ ((r & 7) << 4))) = v;
                }
                __syncthreads();
                #pragma unroll
                for (int h = 0; h < 2; ++h) {
                    const int cb = h * 64 + lhi * 16;
                    bf16x8 af[4], bfr[2];
                    #pragma unroll
                    for (int m = 0; m < 4; ++m) {
                        int r = wm + m * 16 + llo;
                        af[m] = *(const bf16x8*)(a_tile + r * 128 + (cb ^ ((r & 7) << 4)));
                    }
                    #pragma unroll
                    for (int n = 0; n < 2; ++n) {
                        int r = wn + n * 16 + llo;
                        bfr[n] = *(const bf16x8*)(b_tile + r * 128 + (cb ^ ((r & 7) << 4)));
                    }
                    #pragma unroll
                    for (int m = 0; m < 4; ++m)
                        #pragma unroll
                        for (int n = 0; n < 2; ++n)
                            acc[m][n] = __builtin_amdgcn_mfma_f32_16x16x32_bf16(af[m], bfr[n], acc[m][n], 0, 0, 0);
                }
                __syncthreads();
            }

            // emit pair records at deterministic slots
            int aloc[4][4]; int giA[4][4]; float sqA[4][4];
            #pragma unroll
            for (int m = 0; m < 4; ++m)
                #pragma unroll
                for (int r = 0; r < 4; ++r) {
                    int lr = wm + m * 16 + lhi * 4 + r;
                    aloc[m][r] = lr;
                    int gi = idxbuf[baseA + min(lr, cntA - 1)];
                    giA[m][r] = gi;
                    sqA[m][r] = sq[gi];
                }
            int bloc[2]; int gjB[2]; float sqB[2];
            #pragma unroll
            for (int n = 0; n < 2; ++n) {
                int lc = wn + n * 16 + llo;
                bloc[n] = lc;
                int gj = idxbuf[baseB + min(lc, cntB - 1)];
                gjB[n] = gj;
                sqB[n] = sq[gj];
            }
            #pragma unroll
            for (int m = 0; m < 4; ++m)
                #pragma unroll
                for (int n = 0; n < 2; ++n)
                    #pragma unroll
                    for (int r = 0; r < 4; ++r) {
                        int a = si * 128 + aloc[m][r];
                        int b = sj * 128 + bloc[n];
                        bool valid = (aloc[m][r] < cntA) && (bloc[n] < cntB) && (a < b);
                        if (valid) {
                            float g = acc[m][n][r];
                            float d2 = fmaxf(fmaf(-2.f, g, sqA[m][r] + sqB[n]), 0.f);
                            float d = __builtin_amdgcn_sqrtf(d2) * LN2;  // true dist
                            unsigned idx = (unsigned)(pOffs + a * (2 * cnt - a - 1) / 2 + (b - a - 1));
                            if (idx < PAIR_CAP) {
                                uint2 rec;
                                rec.x = __float_as_uint(d);
                                rec.y = ((unsigned)giA[m][r] << 13) | (unsigned)gjB[n];
                                pairs[idx] = rec;
                            }
                        }
                    }
        }
    }
}

// PASS 2: grid-stride over pair records. sum_exp holds sum(exp(-d)); true
// log-term = 1 + log(s_i + s_j). out = sum / npairs / 2.
__global__ __launch_bounds__(256) void pass2_kernel(
    const float* __restrict__ sum_exp,
    const uint2* __restrict__ pairs,
    const unsigned* __restrict__ pairsTotal,
    double* __restrict__ partial2,
    unsigned* __restrict__ ticket,
    float* __restrict__ out)
{
    __shared__ double bsum[4];
    __shared__ bool isLast;
    const int tid = threadIdx.x;
    const int lane = tid & 63, wid = tid >> 6;
    const int NB = gridDim.x;
    const unsigned np = min(*pairsTotal, PAIR_CAP);

    float lsum = 0.f;
    for (unsigned i = blockIdx.x * 256 + tid; i < np; i += NB * 256) {
        uint2 rec = pairs[i];
        float d = __uint_as_float(rec.x);
        int row = rec.y >> 13, col = rec.y & 8191;
        float se = sum_exp[row] + sum_exp[col];
        float L = 1.f + __logf(se) + d;
        L = fmaxf(L, 0.f);
        lsum += L * L;
    }
    #pragma unroll
    for (int off = 1; off < 64; off <<= 1) lsum += __shfl_xor(lsum, off, 64);
    if (lane == 0) bsum[wid] = (double)lsum;
    __syncthreads();
    if (tid == 0) {
        partial2[blockIdx.x] = bsum[0] + bsum[1] + bsum[2] + bsum[3];
        __threadfence();
        isLast = (atomicAdd(ticket, 1u) == (unsigned)(NB - 1));
    }
    __syncthreads();

    if (isLast) {
        __threadfence();
        double tt = (tid < NB) ? partial2[tid] : 0.0;
        #pragma unroll
        for (int off = 1; off < 64; off <<= 1) tt += __shfl_xor(tt, off, 64);
        if (lane == 0) bsum[wid] = tt;
        __syncthreads();
        if (tid == 0) {
            double s = bsum[0] + bsum[1] + bsum[2] + bsum[3];
            unsigned cc = np ? np : 1u;
            out[0] = (float)(s / (double)cc * 0.5);
        }
    }
}

extern "C" void kernel_launch(void* const* d_in, const int* in_sizes, int n_in,
                              void* d_out, int out_size, void* d_ws, size_t ws_size,
                              hipStream_t stream) {
    const float* e = (const float*)d_in[0];
    const int* labels = (const int*)d_in[1];
    const int N = in_sizes[1];                 // 8192
    const int nCb = N / 128;                   // 64
    const int nT = nCb * (nCb + 1) / 2;        // 2080
    const int NL = 256;
    const int nPrep = N / 32;                  // 256
    const int NB2 = 256;                       // pass2 grid

    char* ws = (char*)d_ws;
    float*    sq        = (float*)ws;
    float*    sum_exp   = (float*)(ws + 4 * (size_t)N);
    unsigned short* ebf = (unsigned short*)(ws + 8 * (size_t)N);
    char*     p         = ws + 8 * (size_t)N + 256 * (size_t)N;
    int*      counts    = (int*)p;      p += NL * 4;
    int*      offsets   = (int*)p;      p += NL * 4;
    int*      offsPairs = (int*)p;      p += NL * 4;
    unsigned* pairsTotal= (unsigned*)p;
    unsigned* ticket    = (unsigned*)(p + 4);
    p += 64;
    double*   partial2  = (double*)p;   p += NB2 * 8;
    int*      idxbuf    = (int*)p;      p += (size_t)N * 4;
    p = (char*)(((size_t)p + 15) & ~(size_t)15);
    uint2*    pairs     = (uint2*)p;    // PAIR_CAP * 8 bytes

    setup_kernel<<<nPrep + 1, 256, 0, stream>>>(e, labels, sq, (unsigned*)ebf,
                                                sum_exp, counts, offsets,
                                                offsPairs, pairsTotal,
                                                idxbuf, ticket, N);
    pass1_kernel<<<nT + NL, 512, 0, stream>>>(ebf, sq, labels, sum_exp,
                                              idxbuf, offsets, counts,
                                              offsPairs, pairs, N, nCb, nT);
    pass2_kernel<<<NB2, 256, 0, stream>>>(sum_exp, pairs, pairsTotal,
                                          partial2, ticket, (float*)d_out);
}

// Round 17
// 74.820 us; speedup vs baseline: 1.1610x; 1.1610x over previous
//
#include <hip/hip_runtime.h>
#include <hip/hip_bf16.h>

// LiftedStructureLoss on MI355X (gfx950)
// N=8192, D=128 fp32 embeddings; int labels (0..99); scalar fp32 out.
//
// 4 launches (split kernels => independent regalloc):
//   setup:   prep (sq, bf16, log2e-prescaled; zero sum_exp) + bucket block
//            (hist/scan/scatter + pair-slot scan: offsPairs[L], pairsTotal)
//   pass1a:  upper-triangle 128x128 tiles (R13 hot path, VGPR~52) ->
//            atomic sum_exp of exp(-d) over negatives
//   pass1b:  within-label Gram; pair (a<b) -> deterministic slot (no atomics)
//   pass2:   grid-stride over pair records: relu(1+log(se_i+se_j)+d)^2;
//            ticket: last block -> out = sum / npairs / 2.
//
// Scaling: ebf/sq carry log2e so exp2(-sqrt(d2s)) = exp(-d); true d =
// sqrt(d2s)*ln2. MARGIN's e^1 folds into the +1 inside pass2's log term.

typedef __attribute__((ext_vector_type(8))) short bf16x8;
typedef __attribute__((ext_vector_type(4))) float f32x4;

#if __has_builtin(__builtin_amdgcn_exp2f)
#define EXP2F __builtin_amdgcn_exp2f
#else
#define EXP2F exp2f
#endif

#define PAIR_CAP (1u << 20)   // 1M records (8MB); actual ~332K

__device__ __forceinline__ unsigned short f2bf(float f) {
    unsigned u = __float_as_uint(f);
    u += 0x7fffu + ((u >> 16) & 1u);   // round-to-nearest-even
    return (unsigned short)(u >> 16);
}

// Blocks 0..nPrep-1: prep 32 rows + zero sum_exp slice (block 0: ticket).
// Block nPrep: bucket (256 thr): hist, idx scan, pair-slot scan, scatter.
__global__ __launch_bounds__(256) void setup_kernel(
    const float* __restrict__ e, const int* __restrict__ labels,
    float* __restrict__ sq, unsigned* __restrict__ ebf,
    float* __restrict__ sum_exp,
    int* __restrict__ counts_out, int* __restrict__ offsets_out,
    int* __restrict__ offsPairs_out, unsigned* __restrict__ pairsTotal,
    int* __restrict__ idxbuf, unsigned* __restrict__ ticket, int N)
{
    const int tid = threadIdx.x;
    const float LOG2E = 1.44269504088896341f;
    if ((int)blockIdx.x < (int)gridDim.x - 1) {
        const int lane = tid & 63, wid = tid >> 6;
        if (blockIdx.x == 0 && tid == 0) *ticket = 0u;
        if (tid < 32) sum_exp[blockIdx.x * 32 + tid] = 0.f;
        const int rowbase = (blockIdx.x * 4 + wid) * 8;
        #pragma unroll
        for (int it = 0; it < 8; ++it) {
            int row = rowbase + it;
            if (row >= N) break;
            float2 v = ((const float2*)(e + (size_t)row * 128))[lane];
            v.x *= LOG2E; v.y *= LOG2E;
            float s = v.x * v.x + v.y * v.y;
            #pragma unroll
            for (int off = 1; off < 64; off <<= 1) s += __shfl_xor(s, off, 64);
            if (lane == 0) sq[row] = s;
            unsigned bits = (unsigned)f2bf(v.x) | ((unsigned)f2bf(v.y) << 16);
            ebf[(size_t)row * 64 + lane] = bits;
        }
    } else {
        __shared__ int cnt[256];
        __shared__ int off[256];
        __shared__ int po[256];
        cnt[tid] = 0;
        __syncthreads();
        for (int i = tid; i < N; i += 256)
            atomicAdd(&cnt[(unsigned)labels[i] & 255u], 1);
        __syncthreads();
        if (tid < 64) {
            int base = tid * 4;
            int c0 = cnt[base], c1 = cnt[base+1], c2 = cnt[base+2], c3 = cnt[base+3];
            int s = c0 + c1 + c2 + c3;
            int v = s;
            #pragma unroll
            for (int d = 1; d < 64; d <<= 1) {
                int u = __shfl_up(v, d, 64);
                if (tid >= d) v += u;
            }
            int excl = v - s;
            off[base]     = excl;
            off[base + 1] = excl + c0;
            off[base + 2] = excl + c0 + c1;
            off[base + 3] = excl + c0 + c1 + c2;
            int p0 = c0 * (c0 - 1) / 2, p1 = c1 * (c1 - 1) / 2;
            int p2 = c2 * (c2 - 1) / 2, p3 = c3 * (c3 - 1) / 2;
            int ps = p0 + p1 + p2 + p3;
            int pv = ps;
            #pragma unroll
            for (int d = 1; d < 64; d <<= 1) {
                int u = __shfl_up(pv, d, 64);
                if (tid >= d) pv += u;
            }
            int pexcl = pv - ps;
            po[base]     = pexcl;
            po[base + 1] = pexcl + p0;
            po[base + 2] = pexcl + p0 + p1;
            po[base + 3] = pexcl + p0 + p1 + p2;
            if (tid == 63) *pairsTotal = (unsigned)pv;
        }
        __syncthreads();
        counts_out[tid]    = cnt[tid];
        offsets_out[tid]   = off[tid];
        offsPairs_out[tid] = po[tid];
        cnt[tid] = off[tid];               // reuse as cursor
        __syncthreads();
        for (int i = tid; i < N; i += 256) {
            int l = (unsigned)labels[i] & 255u;
            int p = atomicAdd(&cnt[l], 1);
            idxbuf[p] = i;
        }
    }
}

// PASS 1a (R13 hot path, own compilation unit => VGPR ~52): one 128x128
// upper-triangle tile per block, 512 thr = 8 waves of 64x32.
__global__ __launch_bounds__(512) void pass1a_kernel(
    const unsigned short* __restrict__ ebf,
    const float* __restrict__ sq,
    const int* __restrict__ labels,
    float* __restrict__ sum_exp,
    int N, int nCb)
{
    __shared__ __align__(16) char a_tile[128 * 128];
    __shared__ __align__(16) char b_tile[128 * 128];
    __shared__ float rowsum[128];
    __shared__ float colsum[128];

    const int tid = threadIdx.x;
    const int lane = tid & 63, wid = tid >> 6;

    const int t = blockIdx.x;
    int bi = (int)((2.f * nCb + 1.f - __builtin_amdgcn_sqrtf(
                   (2.f * nCb + 1.f) * (2.f * nCb + 1.f) - 8.f * t)) * 0.5f);
    if (bi < 0) bi = 0;
    if (bi > nCb - 1) bi = nCb - 1;
    while (bi + 1 <= nCb - 1 && (bi + 1) * (2 * nCb - bi) / 2 <= t) ++bi;
    while (bi > 0 && bi * (2 * nCb - bi + 1) / 2 > t) --bi;
    const int bj = bi + (t - bi * (2 * nCb - bi + 1) / 2);
    const bool diag = (bi == bj);
    const int brow = bi * 128, bcol = bj * 128;

    if (tid < 128) { rowsum[tid] = 0.f; colsum[tid] = 0.f; }

    const int wm = (wid >> 2) * 64, wn = (wid & 3) * 32;
    const int lhi = lane >> 4, llo = lane & 15;
    const char* ebfB = (const char*)ebf;

    f32x4 acc[4][2];
    #pragma unroll
    for (int m = 0; m < 4; ++m)
        #pragma unroll
        for (int n = 0; n < 2; ++n)
            acc[m][n] = (f32x4){0.f, 0.f, 0.f, 0.f};

    #pragma unroll
    for (int c = 0; c < 2; ++c) {
        #pragma unroll
        for (int k = 0; k < 4; ++k) {
            int s = wid * 256 + k * 64;
            int tsel = s >> 10;
            int ls = s & 1023;
            int sl = ls + lane;
            int r = sl >> 3, j = sl & 7;
            int grow = (tsel ? bcol : brow) + r;
            const void* g = ebfB + ((size_t)grow << 8) + c * 128 + ((j ^ (r & 7)) << 4);
            char* l = (tsel ? b_tile : a_tile) + ls * 16;
            __builtin_amdgcn_global_load_lds(
                (const __attribute__((address_space(1))) unsigned*)g,
                (__attribute__((address_space(3))) unsigned*)l, 16, 0, 0);
        }
        __syncthreads();

        #pragma unroll
        for (int h = 0; h < 2; ++h) {
            const int cb = h * 64 + lhi * 16;
            bf16x8 af[4], bfr[2];
            #pragma unroll
            for (int m = 0; m < 4; ++m) {
                int r = wm + m * 16 + llo;
                af[m] = *(const bf16x8*)(a_tile + r * 128 + (cb ^ ((r & 7) << 4)));
            }
            #pragma unroll
            for (int n = 0; n < 2; ++n) {
                int r = wn + n * 16 + llo;
                bfr[n] = *(const bf16x8*)(b_tile + r * 128 + (cb ^ ((r & 7) << 4)));
            }
            #pragma unroll
            for (int m = 0; m < 4; ++m)
                #pragma unroll
                for (int n = 0; n < 2; ++n)
                    acc[m][n] = __builtin_amdgcn_mfma_f32_16x16x32_bf16(af[m], bfr[n], acc[m][n], 0, 0, 0);
        }
        __syncthreads();
    }

    const int rowbase = brow + wm;
    float sqr[4][4]; int labr[4][4];
    #pragma unroll
    for (int m = 0; m < 4; ++m)
        #pragma unroll
        for (int r = 0; r < 4; ++r) {
            int row = rowbase + m * 16 + lhi * 4 + r;
            sqr[m][r] = sq[row];
            labr[m][r] = labels[row];
        }
    float sqc[2]; int labc[2];
    #pragma unroll
    for (int n = 0; n < 2; ++n) {
        int col = bcol + wn + n * 16 + llo;
        sqc[n] = sq[col];
        labc[n] = labels[col];
    }

    float wsum[4][4] = {};
    float csum[2] = {};
    #pragma unroll
    for (int m = 0; m < 4; ++m)
        #pragma unroll
        for (int n = 0; n < 2; ++n)
            #pragma unroll
            for (int r = 0; r < 4; ++r) {
                float g = acc[m][n][r];
                float d2 = fmaxf(fmaf(-2.f, g, sqr[m][r] + sqc[n]), 0.f);
                float dist = __builtin_amdgcn_sqrtf(d2);   // log2e * d
                float w = (labr[m][r] != labc[n]) ? EXP2F(0.f - dist) : 0.f;
                wsum[m][r] += w;
                csum[n] += w;
            }
    #pragma unroll
    for (int m = 0; m < 4; ++m)
        #pragma unroll
        for (int r = 0; r < 4; ++r) {
            float s = wsum[m][r];
            #pragma unroll
            for (int off = 1; off < 16; off <<= 1) s += __shfl_xor(s, off, 64);
            if (llo == 0)
                atomicAdd(&rowsum[wm + m * 16 + lhi * 4 + r], s);
        }
    if (!diag) {
        #pragma unroll
        for (int n = 0; n < 2; ++n) {
            float s = csum[n];
            s += __shfl_xor(s, 16, 64);
            s += __shfl_xor(s, 32, 64);
            if (lhi == 0)
                atomicAdd(&colsum[wn + n * 16 + llo], s);
        }
    }
    __syncthreads();
    if (tid < 128) {
        unsafeAtomicAdd(&sum_exp[brow + tid], rowsum[tid]);
        if (!diag)
            unsafeAtomicAdd(&sum_exp[bcol + tid], colsum[tid]);
    }
}

// PASS 1b: within-label pair distances -> deterministic slots. One block per
// label (NL blocks, ~100 active), 512 thr = 8 waves of 64x32.
__global__ __launch_bounds__(512) void pass1b_kernel(
    const unsigned short* __restrict__ ebf,
    const float* __restrict__ sq,
    const int* __restrict__ idxbuf,
    const int* __restrict__ offsets,
    const int* __restrict__ counts,
    const int* __restrict__ offsPairs,
    uint2* __restrict__ pairs)
{
    __shared__ __align__(16) char a_tile[128 * 128];
    __shared__ __align__(16) char b_tile[128 * 128];

    const int tid = threadIdx.x;
    const int lane = tid & 63, wid = tid >> 6;
    const float LN2 = 0.69314718055994531f;
    const int wm = (wid >> 2) * 64, wn = (wid & 3) * 32;
    const int lhi = lane >> 4, llo = lane & 15;
    const char* ebfB = (const char*)ebf;

    const int L = blockIdx.x;
    const int cnt = counts[L], offs = offsets[L];
    const int pOffs = offsPairs[L];
    if (cnt < 2) return;
    const int nSub = (cnt + 127) >> 7;

    for (int si = 0; si < nSub; ++si)
    for (int sj = si; sj < nSub; ++sj) {
        const int baseA = offs + si * 128, baseB = offs + sj * 128;
        const int cntA = min(128, cnt - si * 128);
        const int cntB = min(128, cnt - sj * 128);

        f32x4 acc[4][2];
        #pragma unroll
        for (int m = 0; m < 4; ++m)
            #pragma unroll
            for (int n = 0; n < 2; ++n)
                acc[m][n] = (f32x4){0.f, 0.f, 0.f, 0.f};

        for (int c = 0; c < 2; ++c) {
            #pragma unroll
            for (int i2 = 0; i2 < 4; ++i2) {
                int sl = tid + i2 * 512;
                int tsel = sl >> 10;
                int s = sl & 1023;
                int r = s >> 3, j = s & 7;
                int base = tsel ? baseB : baseA;
                int cc = tsel ? cntB : cntA;
                int gr = idxbuf[base + min(r, cc - 1)];
                uint4 v = *(const uint4*)(ebfB + ((size_t)gr << 8) + c * 128 + (j << 4));
                char* tp = tsel ? b_tile : a_tile;
                *(uint4*)(tp + r * 128 + ((j << 4) ^ ((r & 7) << 4))) = v;
            }
            __syncthreads();
            #pragma unroll
            for (int h = 0; h < 2; ++h) {
                const int cb = h * 64 + lhi * 16;
                bf16x8 af[4], bfr[2];
                #pragma unroll
                for (int m = 0; m < 4; ++m) {
                    int r = wm + m * 16 + llo;
                    af[m] = *(const bf16x8*)(a_tile + r * 128 + (cb ^ ((r & 7) << 4)));
                }
                #pragma unroll
                for (int n = 0; n < 2; ++n) {
                    int r = wn + n * 16 + llo;
                    bfr[n] = *(const bf16x8*)(b_tile + r * 128 + (cb ^ ((r & 7) << 4)));
                }
                #pragma unroll
                for (int m = 0; m < 4; ++m)
                    #pragma unroll
                    for (int n = 0; n < 2; ++n)
                        acc[m][n] = __builtin_amdgcn_mfma_f32_16x16x32_bf16(af[m], bfr[n], acc[m][n], 0, 0, 0);
            }
            __syncthreads();
        }

        int aloc[4][4]; int giA[4][4]; float sqA[4][4];
        #pragma unroll
        for (int m = 0; m < 4; ++m)
            #pragma unroll
            for (int r = 0; r < 4; ++r) {
                int lr = wm + m * 16 + lhi * 4 + r;
                aloc[m][r] = lr;
                int gi = idxbuf[baseA + min(lr, cntA - 1)];
                giA[m][r] = gi;
                sqA[m][r] = sq[gi];
            }
        int bloc[2]; int gjB[2]; float sqB[2];
        #pragma unroll
        for (int n = 0; n < 2; ++n) {
            int lc = wn + n * 16 + llo;
            bloc[n] = lc;
            int gj = idxbuf[baseB + min(lc, cntB - 1)];
            gjB[n] = gj;
            sqB[n] = sq[gj];
        }
        #pragma unroll
        for (int m = 0; m < 4; ++m)
            #pragma unroll
            for (int n = 0; n < 2; ++n)
                #pragma unroll
                for (int r = 0; r < 4; ++r) {
                    int a = si * 128 + aloc[m][r];
                    int b = sj * 128 + bloc[n];
                    bool valid = (aloc[m][r] < cntA) && (bloc[n] < cntB) && (a < b);
                    if (valid) {
                        float g = acc[m][n][r];
                        float d2 = fmaxf(fmaf(-2.f, g, sqA[m][r] + sqB[n]), 0.f);
                        float d = __builtin_amdgcn_sqrtf(d2) * LN2;  // true dist
                        unsigned idx = (unsigned)(pOffs + a * (2 * cnt - a - 1) / 2 + (b - a - 1));
                        if (idx < PAIR_CAP) {
                            uint2 rec;
                            rec.x = __float_as_uint(d);
                            rec.y = ((unsigned)giA[m][r] << 13) | (unsigned)gjB[n];
                            pairs[idx] = rec;
                        }
                    }
                }
    }
}

// PASS 2: grid-stride over pair records. sum_exp holds sum(exp(-d)); true
// log-term = 1 + log(s_i + s_j). out = sum / npairs / 2.
__global__ __launch_bounds__(256) void pass2_kernel(
    const float* __restrict__ sum_exp,
    const uint2* __restrict__ pairs,
    const unsigned* __restrict__ pairsTotal,
    double* __restrict__ partial2,
    unsigned* __restrict__ ticket,
    float* __restrict__ out)
{
    __shared__ double bsum[4];
    __shared__ bool isLast;
    const int tid = threadIdx.x;
    const int lane = tid & 63, wid = tid >> 6;
    const int NB = gridDim.x;
    const unsigned np = min(*pairsTotal, PAIR_CAP);

    float lsum = 0.f;
    for (unsigned i = blockIdx.x * 256 + tid; i < np; i += NB * 256) {
        uint2 rec = pairs[i];
        float d = __uint_as_float(rec.x);
        int row = rec.y >> 13, col = rec.y & 8191;
        float se = sum_exp[row] + sum_exp[col];
        float L = 1.f + __logf(se) + d;
        L = fmaxf(L, 0.f);
        lsum += L * L;
    }
    #pragma unroll
    for (int off = 1; off < 64; off <<= 1) lsum += __shfl_xor(lsum, off, 64);
    if (lane == 0) bsum[wid] = (double)lsum;
    __syncthreads();
    if (tid == 0) {
        partial2[blockIdx.x] = bsum[0] + bsum[1] + bsum[2] + bsum[3];
        __threadfence();
        isLast = (atomicAdd(ticket, 1u) == (unsigned)(NB - 1));
    }
    __syncthreads();

    if (isLast) {
        __threadfence();
        double tt = (tid < NB) ? partial2[tid] : 0.0;
        #pragma unroll
        for (int off = 1; off < 64; off <<= 1) tt += __shfl_xor(tt, off, 64);
        if (lane == 0) bsum[wid] = tt;
        __syncthreads();
        if (tid == 0) {
            double s = bsum[0] + bsum[1] + bsum[2] + bsum[3];
            unsigned cc = np ? np : 1u;
            out[0] = (float)(s / (double)cc * 0.5);
        }
    }
}

extern "C" void kernel_launch(void* const* d_in, const int* in_sizes, int n_in,
                              void* d_out, int out_size, void* d_ws, size_t ws_size,
                              hipStream_t stream) {
    const float* e = (const float*)d_in[0];
    const int* labels = (const int*)d_in[1];
    const int N = in_sizes[1];                 // 8192
    const int nCb = N / 128;                   // 64
    const int nT = nCb * (nCb + 1) / 2;        // 2080
    const int NL = 256;
    const int nPrep = N / 32;                  // 256
    const int NB2 = 256;                       // pass2 grid

    char* ws = (char*)d_ws;
    float*    sq        = (float*)ws;
    float*    sum_exp   = (float*)(ws + 4 * (size_t)N);
    unsigned short* ebf = (unsigned short*)(ws + 8 * (size_t)N);
    char*     p         = ws + 8 * (size_t)N + 256 * (size_t)N;
    int*      counts    = (int*)p;      p += NL * 4;
    int*      offsets   = (int*)p;      p += NL * 4;
    int*      offsPairs = (int*)p;      p += NL * 4;
    unsigned* pairsTotal= (unsigned*)p;
    unsigned* ticket    = (unsigned*)(p + 4);
    p += 64;
    double*   partial2  = (double*)p;   p += NB2 * 8;
    int*      idxbuf    = (int*)p;      p += (size_t)N * 4;
    p = (char*)(((size_t)p + 15) & ~(size_t)15);
    uint2*    pairs     = (uint2*)p;    // PAIR_CAP * 8 bytes

    setup_kernel<<<nPrep + 1, 256, 0, stream>>>(e, labels, sq, (unsigned*)ebf,
                                                sum_exp, counts, offsets,
                                                offsPairs, pairsTotal,
                                                idxbuf, ticket, N);
    pass1b_kernel<<<NL, 512, 0, stream>>>(ebf, sq, idxbuf, offsets, counts,
                                          offsPairs, pairs);
    pass1a_kernel<<<nT, 512, 0, stream>>>(ebf, sq, labels, sum_exp, N, nCb);
    pass2_kernel<<<NB2, 256, 0, stream>>>(sum_exp, pairs, pairsTotal,
                                          partial2, ticket, (float*)d_out);
}